// Round 2
// baseline (24558.403 us; speedup 1.0000x reference)
//
#include <hip/hip_runtime.h>
#include <math.h>

#define HD 256   // hidden_channels
#define FD 128   // graph_convolution_filters
#define RD 32    // radial_dim
#define LNEPS 1e-5f

typedef const float* fp;

// -------- K1: xf = LayerNorm(x @ ntm_w^T + ntm_b) * g + b  -> fp32 [N,F] -----
__global__ __launch_bounds__(128) void node_xform(
    fp __restrict__ x, fp __restrict__ ntm_w, fp __restrict__ ntm_b,
    fp __restrict__ norm_g, fp __restrict__ norm_b,
    float* __restrict__ xf)
{
    const int n = blockIdx.x;
    const int f = threadIdx.x;          // 0..127 output feature
    __shared__ float xs[HD];
    __shared__ float r1[2], r2[2];

    xs[f]      = x[n * HD + f];
    xs[f + FD] = x[n * HD + FD + f];
    __syncthreads();

    const float4* w = (const float4*)(ntm_w + f * HD);   // 256 f32 = 64 float4
    float acc = ntm_b[f];
    #pragma unroll 8
    for (int q = 0; q < HD / 4; ++q) {
        float4 u = w[q];
        const float* xq = xs + q * 4;
        acc += u.x * xq[0] + u.y * xq[1] + u.z * xq[2] + u.w * xq[3];
    }

    // LayerNorm across the 128 features (one per thread, 2 waves)
    float s1 = acc, s2 = acc * acc;
    #pragma unroll
    for (int off = 32; off > 0; off >>= 1) {
        s1 += __shfl_down(s1, off);
        s2 += __shfl_down(s2, off);
    }
    const int lane = f & 63, wv = f >> 6;
    if (lane == 0) { r1[wv] = s1; r2[wv] = s2; }
    __syncthreads();
    const float mu  = (r1[0] + r1[1]) * (1.0f / FD);
    float var = (r2[0] + r2[1]) * (1.0f / FD) - mu * mu;
    const float inv = rsqrtf(var + LNEPS);
    xf[n * FD + f] = (acc - mu) * inv * norm_g[f] + norm_b[f];
}

// -------- K2: per-edge fused MLP + scatter-add ------------------------------
__global__ __launch_bounds__(128) void edge_mlp(
    fp __restrict__ rbf, const int* __restrict__ ei, int E,
    fp __restrict__ rtm_w, fp __restrict__ rtm_b,
    fp __restrict__ l1_w, fp __restrict__ l1_b,
    fp __restrict__ ln_g, fp __restrict__ ln_b,
    fp __restrict__ l2_w, fp __restrict__ l2_b,
    const float* __restrict__ xf, float* __restrict__ agg)
{
    const int e = blockIdx.x;
    const int f = threadIdx.x;          // 0..127
    __shared__ float cat[3 * FD];
    __shared__ float gv[FD];
    __shared__ float srbf[RD];
    __shared__ float r1[2], r2[2];

    const int i = ei[e];
    const int j = ei[E + e];

    cat[f]      = xf[i * FD + f];
    cat[FD + f] = xf[j * FD + f];
    if (f < RD) srbf[f] = rbf[e * RD + f];
    __syncthreads();

    // edge_attr[f] = rbf[e] @ rtm_w[f,:] + rtm_b[f]
    {
        const float4* w = (const float4*)(rtm_w + f * RD);   // 32 f32 = 8 float4
        float ea = rtm_b[f];
        #pragma unroll
        for (int q = 0; q < RD / 4; ++q) {
            float4 u = w[q];
            const float* rq = srbf + q * 4;
            ea += u.x * rq[0] + u.y * rq[1] + u.z * rq[2] + u.w * rq[3];
        }
        cat[2 * FD + f] = ea;
    }
    __syncthreads();

    // linear1: h[f] = cat @ l1_w[f,:] + l1_b[f]
    float h;
    {
        const float4* w = (const float4*)(l1_w + f * 3 * FD);  // 384 f32 = 96 float4
        float acc = l1_b[f];
        #pragma unroll 8
        for (int q = 0; q < 3 * FD / 4; ++q) {
            float4 u = w[q];
            const float* cq = cat + q * 4;
            acc += u.x * cq[0] + u.y * cq[1] + u.z * cq[2] + u.w * cq[3];
        }
        h = acc;
    }

    // LayerNorm over 128
    float s1 = h, s2 = h * h;
    #pragma unroll
    for (int off = 32; off > 0; off >>= 1) {
        s1 += __shfl_down(s1, off);
        s2 += __shfl_down(s2, off);
    }
    const int lane = f & 63, wv = f >> 6;
    if (lane == 0) { r1[wv] = s1; r2[wv] = s2; }
    __syncthreads();
    const float mu  = (r1[0] + r1[1]) * (1.0f / FD);
    float var = (r2[0] + r2[1]) * (1.0f / FD) - mu * mu;
    const float inv = rsqrtf(var + LNEPS);
    const float hn  = (h - mu) * inv * ln_g[f] + ln_b[f];

    // exact GELU
    const float g = 0.5f * hn * (1.0f + erff(hn * 0.70710678118654752f));
    gv[f] = g;
    __syncthreads();

    // linear2: m[f] = gv @ l2_w[f,:] + l2_b[f]
    const float4* w2 = (const float4*)(l2_w + f * FD);       // 128 f32 = 32 float4
    float m = l2_b[f];
    #pragma unroll 8
    for (int q = 0; q < FD / 4; ++q) {
        float4 u = w2[q];
        const float* gq = gv + q * 4;
        m += u.x * gq[0] + u.y * gq[1] + u.z * gq[2] + u.w * gq[3];
    }

    atomicAdd(&agg[j * FD + f], m);
}

// -------- K3: out = agg @ mtn_w^T  -> fp32 [N,H] ----------------------------
__global__ __launch_bounds__(256) void node_out(
    const float* __restrict__ agg, fp __restrict__ mtn_w,
    float* __restrict__ out)
{
    const int n = blockIdx.x;
    const int t = threadIdx.x;          // 0..255 output channel
    __shared__ float a[FD];
    if (t < FD) a[t] = agg[n * FD + t];
    __syncthreads();

    const float4* w = (const float4*)(mtn_w + t * FD);       // 128 f32 = 32 float4
    float acc = 0.0f;
    #pragma unroll 8
    for (int q = 0; q < FD / 4; ++q) {
        float4 u = w[q];
        const float* aq = a + q * 4;
        acc += u.x * aq[0] + u.y * aq[1] + u.z * aq[2] + u.w * aq[3];
    }
    out[n * HD + t] = acc;
}

extern "C" void kernel_launch(void* const* d_in, const int* in_sizes, int n_in,
                              void* d_out, int out_size, void* d_ws, size_t ws_size,
                              hipStream_t stream) {
    fp x      = (fp)d_in[0];                   // [N,H]
    fp rbf    = (fp)d_in[1];                   // [E,R]
    const int* ei = (const int*)d_in[2];       // [2,E]
    fp ntm_w  = (fp)d_in[3];                   // [F,H]
    fp ntm_b  = (fp)d_in[4];
    fp rtm_w  = (fp)d_in[5];                   // [F,R]
    fp rtm_b  = (fp)d_in[6];
    fp norm_g = (fp)d_in[7];
    fp norm_b = (fp)d_in[8];
    fp l1_w   = (fp)d_in[9];                   // [F,3F]
    fp l1_b   = (fp)d_in[10];
    fp ln_g   = (fp)d_in[11];
    fp ln_b   = (fp)d_in[12];
    fp l2_w   = (fp)d_in[13];                  // [F,F]
    fp l2_b   = (fp)d_in[14];
    fp mtn_w  = (fp)d_in[15];                  // [H,F]

    const int N = in_sizes[0] / HD;            // 50000
    const int E = in_sizes[2] / 2;             // 800000

    float* xf  = (float*)d_ws;                 // [N,F] fp32
    float* agg = xf + (size_t)N * FD;          // [N,F] fp32

    hipMemsetAsync((void*)agg, 0, (size_t)N * FD * sizeof(float), stream);

    node_xform<<<N, 128, 0, stream>>>(x, ntm_w, ntm_b, norm_g, norm_b, xf);
    edge_mlp<<<E, 128, 0, stream>>>(rbf, ei, E, rtm_w, rtm_b, l1_w, l1_b,
                                    ln_g, ln_b, l2_w, l2_b, xf, agg);
    node_out<<<N, 256, 0, stream>>>(agg, mtn_w, (float*)d_out);
}

// Round 3
// 1960.797 us; speedup vs baseline: 12.5247x; 12.5247x over previous
//
#include <hip/hip_runtime.h>
#include <math.h>

#define HD 256   // hidden_channels
#define FD 128   // graph_convolution_filters
#define RD 32    // radial_dim
#define K1DIM 288 // fused linear1 K: 128 (xf_i) + 128 (xf_j) + 32 (rbf)
#define EB 64    // edges per tile
#define LNEPS 1e-5f

typedef const float* fp;
typedef unsigned short ushort_t;
typedef __attribute__((ext_vector_type(8))) short s16x8;
typedef __attribute__((ext_vector_type(4))) float f32x4;

__device__ __forceinline__ ushort_t f2bf(float f) {
    union { float f; unsigned int u; } v; v.f = f;
    unsigned int r = v.u + 0x7fffu + ((v.u >> 16) & 1u);   // RNE
    return (ushort_t)(r >> 16);
}

// ---- prep: fuse rtm into l1_w, convert weights to bf16 ---------------------
// W1p [128][288] bf16 : cols 0..255 = l1_w[:, 0:256]; cols 256..287 = l1_w[:,256:384] @ rtm_w
// bias1p [128] f32    : l1_b + l1_w[:,256:384] @ rtm_b
// W2p [128][128] bf16 : l2_w
__global__ __launch_bounds__(128) void prep_weights(
    fp __restrict__ l1_w, fp __restrict__ l1_b,
    fp __restrict__ rtm_w, fp __restrict__ rtm_b, fp __restrict__ l2_w,
    ushort_t* __restrict__ W1p, ushort_t* __restrict__ W2p, float* __restrict__ bias1p)
{
    const int n = blockIdx.x;     // out row
    const int t = threadIdx.x;    // 0..127
    __shared__ float c[FD];
    c[t] = l1_w[n * 3 * FD + 2 * FD + t];
    W1p[n * K1DIM + t]      = f2bf(l1_w[n * 3 * FD + t]);
    W1p[n * K1DIM + FD + t] = f2bf(l1_w[n * 3 * FD + FD + t]);
    W2p[n * FD + t]         = f2bf(l2_w[n * FD + t]);
    __syncthreads();
    if (t < RD) {
        float a = 0.f;
        for (int f = 0; f < FD; ++f) a += c[f] * rtm_w[f * RD + t];
        W1p[n * K1DIM + 2 * FD + t] = f2bf(a);
    }
    if (t == 64) {
        float a = l1_b[n];
        for (int f = 0; f < FD; ++f) a += c[f] * rtm_b[f];
        bias1p[n] = a;
    }
}

// -------- K1: xfb = bf16( LayerNorm(x @ ntm_w^T + ntm_b) * g + b ) ----------
__global__ __launch_bounds__(128) void node_xform(
    fp __restrict__ x, fp __restrict__ ntm_w, fp __restrict__ ntm_b,
    fp __restrict__ norm_g, fp __restrict__ norm_b,
    ushort_t* __restrict__ xfb)
{
    const int n = blockIdx.x;
    const int f = threadIdx.x;
    __shared__ float xs[HD];
    __shared__ float r1[2], r2[2];

    xs[f]      = x[n * HD + f];
    xs[f + FD] = x[n * HD + FD + f];
    __syncthreads();

    const float4* w = (const float4*)(ntm_w + f * HD);
    float acc = ntm_b[f];
    #pragma unroll 8
    for (int q = 0; q < HD / 4; ++q) {
        float4 u = w[q];
        const float* xq = xs + q * 4;
        acc += u.x * xq[0] + u.y * xq[1] + u.z * xq[2] + u.w * xq[3];
    }
    float s1 = acc, s2 = acc * acc;
    #pragma unroll
    for (int off = 32; off > 0; off >>= 1) {
        s1 += __shfl_down(s1, off);
        s2 += __shfl_down(s2, off);
    }
    const int lane = f & 63, wv = f >> 6;
    if (lane == 0) { r1[wv] = s1; r2[wv] = s2; }
    __syncthreads();
    const float mu  = (r1[0] + r1[1]) * (1.0f / FD);
    float var = (r2[0] + r2[1]) * (1.0f / FD) - mu * mu;
    const float inv = rsqrtf(var + LNEPS);
    xfb[n * FD + f] = f2bf((acc - mu) * inv * norm_g[f] + norm_b[f]);
}

// -------- K2: MFMA edge MLP + scatter ---------------------------------------
// Per block: 4 waves, EB=64 edges/tile, grid-stride over tiles.
// GEMM1: [64 x 288] @ W1p^T -> [64 x 128]; LN+GELU; GEMM2: @ W2p^T -> [64 x 128]
// Wave w owns output cols [32w, 32w+32) (2 n-tiles of 16).
__global__ __launch_bounds__(256, 2) void edge_mlp_mfma(
    fp __restrict__ rbf, const int* __restrict__ ei, int E, int ntiles,
    const ushort_t* __restrict__ W1p, const ushort_t* __restrict__ W2p,
    const float* __restrict__ bias1p,
    fp __restrict__ ln_g, fp __restrict__ ln_b, fp __restrict__ l2_b,
    const ushort_t* __restrict__ xfb, float* __restrict__ agg)
{
    __shared__ __attribute__((aligned(16))) ushort_t A1[EB][K1DIM + 8]; // 296
    __shared__ __attribute__((aligned(16))) ushort_t A2[EB][FD + 8];    // 136
    __shared__ __attribute__((aligned(16))) float ssum[EB][4];
    __shared__ __attribute__((aligned(16))) float ssq[EB][4];
    __shared__ float smu[EB], sinv[EB];
    __shared__ int jrow[EB];

    const int t    = threadIdx.x;
    const int w    = t >> 6;          // wave 0..3
    const int lane = t & 63;
    const int q    = lane >> 4;       // quad 0..3
    const int lq   = lane & 15;
    const int n0   = w * 32;

    // ---- persistent per-wave weight fragments (registers) ----
    s16x8 b1[9][2];
    #pragma unroll
    for (int s = 0; s < 2; ++s) {
        const int n = n0 + s * 16 + lq;
        #pragma unroll
        for (int kt = 0; kt < 9; ++kt)
            b1[kt][s] = *(const s16x8*)(W1p + n * K1DIM + kt * 32 + q * 8);
    }
    s16x8 b2[4][2];
    #pragma unroll
    for (int s = 0; s < 2; ++s) {
        const int n = n0 + s * 16 + lq;
        #pragma unroll
        for (int kt = 0; kt < 4; ++kt)
            b2[kt][s] = *(const s16x8*)(W2p + n * FD + kt * 32 + q * 8);
    }
    float g_ln[2], bb_ln[2], bias1v[2], bias2v[2];
    #pragma unroll
    for (int s = 0; s < 2; ++s) {
        const int n = n0 + s * 16 + lq;
        g_ln[s]   = ln_g[n];
        bb_ln[s]  = ln_b[n];
        bias1v[s] = bias1p[n];
        bias2v[s] = l2_b[n];
    }

    for (int tile = blockIdx.x; tile < ntiles; tile += gridDim.x) {
        // ---- stage A1: [xf_i | xf_j | rbf] as bf16, 4 threads per edge ----
        {
            const int el = t >> 2, p = t & 3;
            const long e = (long)tile * EB + el;
            if (e < E) {
                const int inode = ei[e];
                const int jnode = ei[(long)E + e];
                if (p == 0) jrow[el] = jnode;
                const s16x8* si = (const s16x8*)(xfb + (long)inode * FD + p * 32);
                const s16x8* sj = (const s16x8*)(xfb + (long)jnode * FD + p * 32);
                s16x8* di = (s16x8*)&A1[el][p * 32];
                s16x8* dj = (s16x8*)&A1[el][FD + p * 32];
                #pragma unroll
                for (int c = 0; c < 4; ++c) { di[c] = si[c]; dj[c] = sj[c]; }
                const float* rs = rbf + e * RD + p * 8;
                ushort_t tmp[8];
                #pragma unroll
                for (int c = 0; c < 8; ++c) tmp[c] = f2bf(rs[c]);
                *(s16x8*)&A1[el][2 * FD + p * 8] = *(s16x8*)tmp;
            } else {
                if (p == 0) jrow[el] = -1;
                s16x8 z = (s16x8)0;
                #pragma unroll
                for (int c = 0; c < 4; ++c) {
                    ((s16x8*)&A1[el][p * 32])[c] = z;
                    ((s16x8*)&A1[el][FD + p * 32])[c] = z;
                }
                *(s16x8*)&A1[el][2 * FD + p * 8] = z;
            }
        }
        __syncthreads();

        // ---- GEMM1: c1[mt][s] covers rows mt*16.., cols n0+16s.. ----
        f32x4 c1[4][2];
        #pragma unroll
        for (int mt = 0; mt < 4; ++mt)
            #pragma unroll
            for (int s = 0; s < 2; ++s) {
                c1[mt][s][0] = bias1v[s]; c1[mt][s][1] = bias1v[s];
                c1[mt][s][2] = bias1v[s]; c1[mt][s][3] = bias1v[s];
            }
        #pragma unroll
        for (int kt = 0; kt < 9; ++kt) {
            s16x8 a[4];
            #pragma unroll
            for (int mt = 0; mt < 4; ++mt)
                a[mt] = *(const s16x8*)&A1[mt * 16 + lq][kt * 32 + q * 8];
            #pragma unroll
            for (int mt = 0; mt < 4; ++mt)
                #pragma unroll
                for (int s = 0; s < 2; ++s)
                    c1[mt][s] = __builtin_amdgcn_mfma_f32_16x16x32_bf16(
                        a[mt], b1[kt][s], c1[mt][s], 0, 0, 0);
        }

        // ---- LN stats: butterfly over the 16 lanes of each quad ----
        {
            float sv[4][4], sq2[4][4];
            #pragma unroll
            for (int mt = 0; mt < 4; ++mt)
                #pragma unroll
                for (int r = 0; r < 4; ++r) {
                    float a = c1[mt][0][r], b = c1[mt][1][r];
                    sv[mt][r]  = a + b;
                    sq2[mt][r] = a * a + b * b;
                }
            #pragma unroll
            for (int m = 1; m < 16; m <<= 1)
                #pragma unroll
                for (int mt = 0; mt < 4; ++mt)
                    #pragma unroll
                    for (int r = 0; r < 4; ++r) {
                        sv[mt][r]  += __shfl_xor(sv[mt][r], m);
                        sq2[mt][r] += __shfl_xor(sq2[mt][r], m);
                    }
            if (lq == 0) {
                #pragma unroll
                for (int mt = 0; mt < 4; ++mt)
                    #pragma unroll
                    for (int r = 0; r < 4; ++r) {
                        const int row = mt * 16 + q * 4 + r;
                        ssum[row][w] = sv[mt][r];
                        ssq[row][w]  = sq2[mt][r];
                    }
            }
        }
        __syncthreads();
        if (t < EB) {
            float4 s4 = *(const float4*)ssum[t];
            float4 q4 = *(const float4*)ssq[t];
            const float tot  = s4.x + s4.y + s4.z + s4.w;
            const float totq = q4.x + q4.y + q4.z + q4.w;
            const float mu   = tot * (1.0f / FD);
            float var = totq * (1.0f / FD) - mu * mu;
            smu[t]  = mu;
            sinv[t] = rsqrtf(var + LNEPS);
        }
        __syncthreads();

        // ---- normalize + GELU -> A2 (bf16) ----
        #pragma unroll
        for (int mt = 0; mt < 4; ++mt)
            #pragma unroll
            for (int r = 0; r < 4; ++r) {
                const int row = mt * 16 + q * 4 + r;
                const float mu = smu[row], inv = sinv[row];
                #pragma unroll
                for (int s = 0; s < 2; ++s) {
                    float hn = (c1[mt][s][r] - mu) * inv * g_ln[s] + bb_ln[s];
                    float ge = 0.5f * hn * (1.0f + erff(hn * 0.70710678118654752f));
                    A2[row][n0 + s * 16 + lq] = f2bf(ge);
                }
            }
        __syncthreads();

        // ---- GEMM2 ----
        f32x4 c2[4][2];
        #pragma unroll
        for (int mt = 0; mt < 4; ++mt)
            #pragma unroll
            for (int s = 0; s < 2; ++s) {
                c2[mt][s][0] = bias2v[s]; c2[mt][s][1] = bias2v[s];
                c2[mt][s][2] = bias2v[s]; c2[mt][s][3] = bias2v[s];
            }
        #pragma unroll
        for (int kt = 0; kt < 4; ++kt) {
            s16x8 a[4];
            #pragma unroll
            for (int mt = 0; mt < 4; ++mt)
                a[mt] = *(const s16x8*)&A2[mt * 16 + lq][kt * 32 + q * 8];
            #pragma unroll
            for (int mt = 0; mt < 4; ++mt)
                #pragma unroll
                for (int s = 0; s < 2; ++s)
                    c2[mt][s] = __builtin_amdgcn_mfma_f32_16x16x32_bf16(
                        a[mt], b2[kt][s], c2[mt][s], 0, 0, 0);
        }

        // ---- scatter: agg[j, col] += c2 ----
        #pragma unroll
        for (int mt = 0; mt < 4; ++mt)
            #pragma unroll
            for (int r = 0; r < 4; ++r) {
                const int row = mt * 16 + q * 4 + r;
                const int jj = jrow[row];
                if (jj >= 0) {
                    #pragma unroll
                    for (int s = 0; s < 2; ++s)
                        atomicAdd(&agg[(long)jj * FD + n0 + s * 16 + lq],
                                  c2[mt][s][r]);
                }
            }
        __syncthreads();   // protect A1/A2/jrow before next tile's staging
    }
}

// -------- K3: out = agg @ mtn_w^T  -> fp32 [N,H] ----------------------------
__global__ __launch_bounds__(256) void node_out(
    const float* __restrict__ agg, fp __restrict__ mtn_w,
    float* __restrict__ out)
{
    const int n = blockIdx.x;
    const int t = threadIdx.x;
    __shared__ float a[FD];
    if (t < FD) a[t] = agg[n * FD + t];
    __syncthreads();

    const float4* w = (const float4*)(mtn_w + t * FD);
    float acc = 0.0f;
    #pragma unroll 8
    for (int q = 0; q < FD / 4; ++q) {
        float4 u = w[q];
        const float* aq = a + q * 4;
        acc += u.x * aq[0] + u.y * aq[1] + u.z * aq[2] + u.w * aq[3];
    }
    out[n * HD + t] = acc;
}

extern "C" void kernel_launch(void* const* d_in, const int* in_sizes, int n_in,
                              void* d_out, int out_size, void* d_ws, size_t ws_size,
                              hipStream_t stream) {
    fp x      = (fp)d_in[0];
    fp rbf    = (fp)d_in[1];
    const int* ei = (const int*)d_in[2];
    fp ntm_w  = (fp)d_in[3];
    fp ntm_b  = (fp)d_in[4];
    fp rtm_w  = (fp)d_in[5];
    fp rtm_b  = (fp)d_in[6];
    fp norm_g = (fp)d_in[7];
    fp norm_b = (fp)d_in[8];
    fp l1_w   = (fp)d_in[9];
    fp l1_b   = (fp)d_in[10];
    fp ln_g   = (fp)d_in[11];
    fp ln_b   = (fp)d_in[12];
    fp l2_w   = (fp)d_in[13];
    fp l2_b   = (fp)d_in[14];
    fp mtn_w  = (fp)d_in[15];

    const int N = in_sizes[0] / HD;            // 50000
    const int E = in_sizes[2] / 2;             // 800000

    // workspace layout
    char* wp = (char*)d_ws;
    float*    agg    = (float*)wp;              wp += (size_t)N * FD * 4;
    ushort_t* xfb    = (ushort_t*)wp;           wp += (size_t)N * FD * 2;
    ushort_t* W1p    = (ushort_t*)wp;           wp += (size_t)FD * K1DIM * 2;
    ushort_t* W2p    = (ushort_t*)wp;           wp += (size_t)FD * FD * 2;
    float*    bias1p = (float*)wp;              wp += FD * 4;

    hipMemsetAsync((void*)agg, 0, (size_t)N * FD * sizeof(float), stream);

    prep_weights<<<FD, 128, 0, stream>>>(l1_w, l1_b, rtm_w, rtm_b, l2_w,
                                         W1p, W2p, bias1p);
    node_xform<<<N, 128, 0, stream>>>(x, ntm_w, ntm_b, norm_g, norm_b, xfb);

    const int ntiles = (E + EB - 1) / EB;      // 12500
    const int nblk = ntiles < 500 ? ntiles : 500;
    edge_mlp_mfma<<<nblk, 256, 0, stream>>>(rbf, ei, E, ntiles, W1p, W2p, bias1p,
                                            ln_g, ln_b, l2_b, xfb, agg);
    node_out<<<N, 256, 0, stream>>>(agg, mtn_w, (float*)d_out);
}

// Round 4
// 644.848 us; speedup vs baseline: 38.0840x; 3.0407x over previous
//
#include <hip/hip_runtime.h>
#include <math.h>

#define HD 256   // hidden_channels
#define FD 128   // graph_convolution_filters
#define RD 32    // radial_dim
#define K1DIM 288 // fused linear1 K: 128 (xf_i) + 128 (xf_j) + 32 (rbf)
#define EB 64    // edges per tile
#define LNEPS 1e-5f

typedef const float* fp;
typedef unsigned short ushort_t;
typedef __attribute__((ext_vector_type(8))) short s16x8;
typedef __attribute__((ext_vector_type(4))) float f32x4;

__device__ __forceinline__ ushort_t f2bf(float f) {
    union { float f; unsigned int u; } v; v.f = f;
    unsigned int r = v.u + 0x7fffu + ((v.u >> 16) & 1u);   // RNE
    return (ushort_t)(r >> 16);
}

// ---- prep: fuse rtm into l1_w; convert all GEMM weights to bf16 ------------
__global__ __launch_bounds__(128) void prep_weights(
    fp __restrict__ l1_w, fp __restrict__ l1_b,
    fp __restrict__ rtm_w, fp __restrict__ rtm_b, fp __restrict__ l2_w,
    fp __restrict__ ntm_w, fp __restrict__ mtn_w,
    ushort_t* __restrict__ W1p, ushort_t* __restrict__ W2p,
    float* __restrict__ bias1p,
    ushort_t* __restrict__ W0p, ushort_t* __restrict__ Wm)
{
    const int n = blockIdx.x;     // 0..127
    const int t = threadIdx.x;    // 0..127
    __shared__ float c[FD];
    c[t] = l1_w[n * 3 * FD + 2 * FD + t];
    W1p[n * K1DIM + t]      = f2bf(l1_w[n * 3 * FD + t]);
    W1p[n * K1DIM + FD + t] = f2bf(l1_w[n * 3 * FD + FD + t]);
    W2p[n * FD + t]         = f2bf(l2_w[n * FD + t]);
    W0p[n * HD + t]         = f2bf(ntm_w[n * HD + t]);
    W0p[n * HD + FD + t]    = f2bf(ntm_w[n * HD + FD + t]);
    Wm[n * FD + t]              = f2bf(mtn_w[n * FD + t]);
    Wm[(n + FD) * FD + t]       = f2bf(mtn_w[(n + FD) * FD + t]);
    __syncthreads();
    if (t < RD) {
        float a = 0.f;
        for (int f = 0; f < FD; ++f) a += c[f] * rtm_w[f * RD + t];
        W1p[n * K1DIM + 2 * FD + t] = f2bf(a);
    }
    if (t == 64) {
        float a = l1_b[n];
        for (int f = 0; f < FD; ++f) a += c[f] * rtm_b[f];
        bias1p[n] = a;
    }
}

// -------- K1: xfb = bf16( LN(x @ ntm_w^T + ntm_b) * g + b )  (MFMA) ---------
// 64 nodes per tile; A = x-tile (contiguous rows) fp32->bf16 in LDS;
// B = W0p held in registers per wave (wave w owns cols w*32..w*32+31).
__global__ __launch_bounds__(256, 2) void node_xform_mfma(
    fp __restrict__ x, const ushort_t* __restrict__ W0p,
    fp __restrict__ ntm_b, fp __restrict__ norm_g, fp __restrict__ norm_b,
    ushort_t* __restrict__ xfb, int N, int ntiles)
{
    __shared__ __attribute__((aligned(16))) ushort_t A[EB][HD + 8];
    __shared__ __attribute__((aligned(16))) float ssum[EB][4];
    __shared__ __attribute__((aligned(16))) float ssq[EB][4];
    __shared__ float smu[EB], sinv[EB];

    const int t    = threadIdx.x;
    const int w    = t >> 6;
    const int lane = t & 63;
    const int q    = lane >> 4;
    const int lq   = lane & 15;
    const int n0   = w * 32;

    s16x8 b0[8][2];
    float biasv[2], gv[2], bv[2];
    #pragma unroll
    for (int s = 0; s < 2; ++s) {
        const int n = n0 + s * 16 + lq;
        #pragma unroll
        for (int kt = 0; kt < 8; ++kt)
            b0[kt][s] = *(const s16x8*)(W0p + n * HD + kt * 32 + q * 8);
        biasv[s] = ntm_b[n];
        gv[s]    = norm_g[n];
        bv[s]    = norm_b[n];
    }

    for (int tile = blockIdx.x; tile < ntiles; tile += gridDim.x) {
        // ---- stage A: rows are contiguous nodes -> fully coalesced ----
        {
            const int row = t >> 2, cc = (t & 3) * 64;
            const long n = (long)tile * EB + row;
            if (n < N) {
                const float4* src = (const float4*)(x + n * HD + cc);
                #pragma unroll
                for (int c = 0; c < 8; ++c) {
                    float4 u0 = src[2 * c], u1 = src[2 * c + 1];
                    ushort_t tmp[8] = { f2bf(u0.x), f2bf(u0.y), f2bf(u0.z), f2bf(u0.w),
                                        f2bf(u1.x), f2bf(u1.y), f2bf(u1.z), f2bf(u1.w) };
                    *(s16x8*)&A[row][cc + c * 8] = *(s16x8*)tmp;
                }
            } else {
                s16x8 z = (s16x8)0;
                #pragma unroll
                for (int c = 0; c < 8; ++c)
                    *(s16x8*)&A[row][cc + c * 8] = z;
            }
        }
        __syncthreads();

        // ---- GEMM ----
        f32x4 c1[4][2];
        #pragma unroll
        for (int mt = 0; mt < 4; ++mt)
            #pragma unroll
            for (int s = 0; s < 2; ++s) {
                c1[mt][s][0] = biasv[s]; c1[mt][s][1] = biasv[s];
                c1[mt][s][2] = biasv[s]; c1[mt][s][3] = biasv[s];
            }
        #pragma unroll
        for (int kt = 0; kt < 8; ++kt) {
            s16x8 a[4];
            #pragma unroll
            for (int mt = 0; mt < 4; ++mt)
                a[mt] = *(const s16x8*)&A[mt * 16 + lq][kt * 32 + q * 8];
            #pragma unroll
            for (int mt = 0; mt < 4; ++mt)
                #pragma unroll
                for (int s = 0; s < 2; ++s)
                    c1[mt][s] = __builtin_amdgcn_mfma_f32_16x16x32_bf16(
                        a[mt], b0[kt][s], c1[mt][s], 0, 0, 0);
        }

        // ---- LN stats ----
        {
            float sv[4][4], sq2[4][4];
            #pragma unroll
            for (int mt = 0; mt < 4; ++mt)
                #pragma unroll
                for (int r = 0; r < 4; ++r) {
                    float a = c1[mt][0][r], b = c1[mt][1][r];
                    sv[mt][r]  = a + b;
                    sq2[mt][r] = a * a + b * b;
                }
            #pragma unroll
            for (int m = 1; m < 16; m <<= 1)
                #pragma unroll
                for (int mt = 0; mt < 4; ++mt)
                    #pragma unroll
                    for (int r = 0; r < 4; ++r) {
                        sv[mt][r]  += __shfl_xor(sv[mt][r], m);
                        sq2[mt][r] += __shfl_xor(sq2[mt][r], m);
                    }
            if (lq == 0) {
                #pragma unroll
                for (int mt = 0; mt < 4; ++mt)
                    #pragma unroll
                    for (int r = 0; r < 4; ++r) {
                        const int row = mt * 16 + q * 4 + r;
                        ssum[row][w] = sv[mt][r];
                        ssq[row][w]  = sq2[mt][r];
                    }
            }
        }
        __syncthreads();
        if (t < EB) {
            float4 s4 = *(const float4*)ssum[t];
            float4 q4 = *(const float4*)ssq[t];
            const float tot  = s4.x + s4.y + s4.z + s4.w;
            const float totq = q4.x + q4.y + q4.z + q4.w;
            const float mu   = tot * (1.0f / FD);
            float var = totq * (1.0f / FD) - mu * mu;
            smu[t]  = mu;
            sinv[t] = rsqrtf(var + LNEPS);
        }
        __syncthreads();

        // ---- normalize -> xfb ----
        #pragma unroll
        for (int mt = 0; mt < 4; ++mt)
            #pragma unroll
            for (int r = 0; r < 4; ++r) {
                const int row = mt * 16 + q * 4 + r;
                const long n = (long)tile * EB + row;
                if (n < N) {
                    const float mu = smu[row], inv = sinv[row];
                    #pragma unroll
                    for (int s = 0; s < 2; ++s)
                        xfb[n * FD + n0 + s * 16 + lq] =
                            f2bf((c1[mt][s][r] - mu) * inv * gv[s] + bv[s]);
                }
            }
        __syncthreads();
    }
}

// -------- K2: MFMA edge MLP + scatter (unchanged from R3) -------------------
__global__ __launch_bounds__(256, 2) void edge_mlp_mfma(
    fp __restrict__ rbf, const int* __restrict__ ei, int E, int ntiles,
    const ushort_t* __restrict__ W1p, const ushort_t* __restrict__ W2p,
    const float* __restrict__ bias1p,
    fp __restrict__ ln_g, fp __restrict__ ln_b, fp __restrict__ l2_b,
    const ushort_t* __restrict__ xfb, float* __restrict__ agg)
{
    __shared__ __attribute__((aligned(16))) ushort_t A1[EB][K1DIM + 8];
    __shared__ __attribute__((aligned(16))) ushort_t A2[EB][FD + 8];
    __shared__ __attribute__((aligned(16))) float ssum[EB][4];
    __shared__ __attribute__((aligned(16))) float ssq[EB][4];
    __shared__ float smu[EB], sinv[EB];
    __shared__ int jrow[EB];

    const int t    = threadIdx.x;
    const int w    = t >> 6;
    const int lane = t & 63;
    const int q    = lane >> 4;
    const int lq   = lane & 15;
    const int n0   = w * 32;

    s16x8 b1[9][2];
    #pragma unroll
    for (int s = 0; s < 2; ++s) {
        const int n = n0 + s * 16 + lq;
        #pragma unroll
        for (int kt = 0; kt < 9; ++kt)
            b1[kt][s] = *(const s16x8*)(W1p + n * K1DIM + kt * 32 + q * 8);
    }
    s16x8 b2[4][2];
    #pragma unroll
    for (int s = 0; s < 2; ++s) {
        const int n = n0 + s * 16 + lq;
        #pragma unroll
        for (int kt = 0; kt < 4; ++kt)
            b2[kt][s] = *(const s16x8*)(W2p + n * FD + kt * 32 + q * 8);
    }
    float g_ln[2], bb_ln[2], bias1v[2], bias2v[2];
    #pragma unroll
    for (int s = 0; s < 2; ++s) {
        const int n = n0 + s * 16 + lq;
        g_ln[s]   = ln_g[n];
        bb_ln[s]  = ln_b[n];
        bias1v[s] = bias1p[n];
        bias2v[s] = l2_b[n];
    }

    for (int tile = blockIdx.x; tile < ntiles; tile += gridDim.x) {
        {
            const int el = t >> 2, p = t & 3;
            const long e = (long)tile * EB + el;
            if (e < E) {
                const int inode = ei[e];
                const int jnode = ei[(long)E + e];
                if (p == 0) jrow[el] = jnode;
                const s16x8* si = (const s16x8*)(xfb + (long)inode * FD + p * 32);
                const s16x8* sj = (const s16x8*)(xfb + (long)jnode * FD + p * 32);
                s16x8* di = (s16x8*)&A1[el][p * 32];
                s16x8* dj = (s16x8*)&A1[el][FD + p * 32];
                #pragma unroll
                for (int c = 0; c < 4; ++c) { di[c] = si[c]; dj[c] = sj[c]; }
                const float* rs = rbf + e * RD + p * 8;
                ushort_t tmp[8];
                #pragma unroll
                for (int c = 0; c < 8; ++c) tmp[c] = f2bf(rs[c]);
                *(s16x8*)&A1[el][2 * FD + p * 8] = *(s16x8*)tmp;
            } else {
                if (p == 0) jrow[el] = -1;
                s16x8 z = (s16x8)0;
                #pragma unroll
                for (int c = 0; c < 4; ++c) {
                    ((s16x8*)&A1[el][p * 32])[c] = z;
                    ((s16x8*)&A1[el][FD + p * 32])[c] = z;
                }
                *(s16x8*)&A1[el][2 * FD + p * 8] = z;
            }
        }
        __syncthreads();

        f32x4 c1[4][2];
        #pragma unroll
        for (int mt = 0; mt < 4; ++mt)
            #pragma unroll
            for (int s = 0; s < 2; ++s) {
                c1[mt][s][0] = bias1v[s]; c1[mt][s][1] = bias1v[s];
                c1[mt][s][2] = bias1v[s]; c1[mt][s][3] = bias1v[s];
            }
        #pragma unroll
        for (int kt = 0; kt < 9; ++kt) {
            s16x8 a[4];
            #pragma unroll
            for (int mt = 0; mt < 4; ++mt)
                a[mt] = *(const s16x8*)&A1[mt * 16 + lq][kt * 32 + q * 8];
            #pragma unroll
            for (int mt = 0; mt < 4; ++mt)
                #pragma unroll
                for (int s = 0; s < 2; ++s)
                    c1[mt][s] = __builtin_amdgcn_mfma_f32_16x16x32_bf16(
                        a[mt], b1[kt][s], c1[mt][s], 0, 0, 0);
        }

        {
            float sv[4][4], sq2[4][4];
            #pragma unroll
            for (int mt = 0; mt < 4; ++mt)
                #pragma unroll
                for (int r = 0; r < 4; ++r) {
                    float a = c1[mt][0][r], b = c1[mt][1][r];
                    sv[mt][r]  = a + b;
                    sq2[mt][r] = a * a + b * b;
                }
            #pragma unroll
            for (int m = 1; m < 16; m <<= 1)
                #pragma unroll
                for (int mt = 0; mt < 4; ++mt)
                    #pragma unroll
                    for (int r = 0; r < 4; ++r) {
                        sv[mt][r]  += __shfl_xor(sv[mt][r], m);
                        sq2[mt][r] += __shfl_xor(sq2[mt][r], m);
                    }
            if (lq == 0) {
                #pragma unroll
                for (int mt = 0; mt < 4; ++mt)
                    #pragma unroll
                    for (int r = 0; r < 4; ++r) {
                        const int row = mt * 16 + q * 4 + r;
                        ssum[row][w] = sv[mt][r];
                        ssq[row][w]  = sq2[mt][r];
                    }
            }
        }
        __syncthreads();
        if (t < EB) {
            float4 s4 = *(const float4*)ssum[t];
            float4 q4 = *(const float4*)ssq[t];
            const float tot  = s4.x + s4.y + s4.z + s4.w;
            const float totq = q4.x + q4.y + q4.z + q4.w;
            const float mu   = tot * (1.0f / FD);
            float var = totq * (1.0f / FD) - mu * mu;
            smu[t]  = mu;
            sinv[t] = rsqrtf(var + LNEPS);
        }
        __syncthreads();

        #pragma unroll
        for (int mt = 0; mt < 4; ++mt)
            #pragma unroll
            for (int r = 0; r < 4; ++r) {
                const int row = mt * 16 + q * 4 + r;
                const float mu = smu[row], inv = sinv[row];
                #pragma unroll
                for (int s = 0; s < 2; ++s) {
                    float hn = (c1[mt][s][r] - mu) * inv * g_ln[s] + bb_ln[s];
                    float ge = 0.5f * hn * (1.0f + erff(hn * 0.70710678118654752f));
                    A2[row][n0 + s * 16 + lq] = f2bf(ge);
                }
            }
        __syncthreads();

        f32x4 c2[4][2];
        #pragma unroll
        for (int mt = 0; mt < 4; ++mt)
            #pragma unroll
            for (int s = 0; s < 2; ++s) {
                c2[mt][s][0] = bias2v[s]; c2[mt][s][1] = bias2v[s];
                c2[mt][s][2] = bias2v[s]; c2[mt][s][3] = bias2v[s];
            }
        #pragma unroll
        for (int kt = 0; kt < 4; ++kt) {
            s16x8 a[4];
            #pragma unroll
            for (int mt = 0; mt < 4; ++mt)
                a[mt] = *(const s16x8*)&A2[mt * 16 + lq][kt * 32 + q * 8];
            #pragma unroll
            for (int mt = 0; mt < 4; ++mt)
                #pragma unroll
                for (int s = 0; s < 2; ++s)
                    c2[mt][s] = __builtin_amdgcn_mfma_f32_16x16x32_bf16(
                        a[mt], b2[kt][s], c2[mt][s], 0, 0, 0);
        }

        #pragma unroll
        for (int mt = 0; mt < 4; ++mt)
            #pragma unroll
            for (int r = 0; r < 4; ++r) {
                const int row = mt * 16 + q * 4 + r;
                const int jj = jrow[row];
                if (jj >= 0) {
                    #pragma unroll
                    for (int s = 0; s < 2; ++s)
                        atomicAdd(&agg[(long)jj * FD + n0 + s * 16 + lq],
                                  c2[mt][s][r]);
                }
            }
        __syncthreads();
    }
}

// -------- K3: out = agg @ mtn_w^T  (MFMA, fp32 out) -------------------------
// 64 nodes/tile; wave w owns out cols w*64 .. w*64+63 (4 col-tiles of 16).
__global__ __launch_bounds__(256, 2) void node_out_mfma(
    const float* __restrict__ agg, const ushort_t* __restrict__ Wm,
    float* __restrict__ out, int N, int ntiles)
{
    __shared__ __attribute__((aligned(16))) ushort_t A[EB][FD + 8];

    const int t    = threadIdx.x;
    const int w    = t >> 6;
    const int lane = t & 63;
    const int q    = lane >> 4;
    const int lq   = lane & 15;
    const int n0   = w * 64;

    s16x8 bm[4][4];
    #pragma unroll
    for (int s = 0; s < 4; ++s) {
        const int h = n0 + s * 16 + lq;
        #pragma unroll
        for (int kt = 0; kt < 4; ++kt)
            bm[kt][s] = *(const s16x8*)(Wm + h * FD + kt * 32 + q * 8);
    }

    for (int tile = blockIdx.x; tile < ntiles; tile += gridDim.x) {
        {
            const int row = t >> 2, cc = (t & 3) * 32;
            const long n = (long)tile * EB + row;
            if (n < N) {
                const float4* src = (const float4*)(agg + n * FD + cc);
                #pragma unroll
                for (int c = 0; c < 4; ++c) {
                    float4 u0 = src[2 * c], u1 = src[2 * c + 1];
                    ushort_t tmp[8] = { f2bf(u0.x), f2bf(u0.y), f2bf(u0.z), f2bf(u0.w),
                                        f2bf(u1.x), f2bf(u1.y), f2bf(u1.z), f2bf(u1.w) };
                    *(s16x8*)&A[row][cc + c * 8] = *(s16x8*)tmp;
                }
            } else {
                s16x8 z = (s16x8)0;
                #pragma unroll
                for (int c = 0; c < 4; ++c)
                    *(s16x8*)&A[row][cc + c * 8] = z;
            }
        }
        __syncthreads();

        f32x4 cacc[4][4];
        #pragma unroll
        for (int mt = 0; mt < 4; ++mt)
            #pragma unroll
            for (int s = 0; s < 4; ++s)
                cacc[mt][s] = (f32x4)0.0f;
        #pragma unroll
        for (int kt = 0; kt < 4; ++kt) {
            s16x8 a[4];
            #pragma unroll
            for (int mt = 0; mt < 4; ++mt)
                a[mt] = *(const s16x8*)&A[mt * 16 + lq][kt * 32 + q * 8];
            #pragma unroll
            for (int mt = 0; mt < 4; ++mt)
                #pragma unroll
                for (int s = 0; s < 4; ++s)
                    cacc[mt][s] = __builtin_amdgcn_mfma_f32_16x16x32_bf16(
                        a[mt], bm[kt][s], cacc[mt][s], 0, 0, 0);
        }

        #pragma unroll
        for (int mt = 0; mt < 4; ++mt)
            #pragma unroll
            for (int r = 0; r < 4; ++r) {
                const long n = (long)tile * EB + mt * 16 + q * 4 + r;
                if (n < N) {
                    #pragma unroll
                    for (int s = 0; s < 4; ++s)
                        out[n * HD + n0 + s * 16 + lq] = cacc[mt][s][r];
                }
            }
        __syncthreads();
    }
}

extern "C" void kernel_launch(void* const* d_in, const int* in_sizes, int n_in,
                              void* d_out, int out_size, void* d_ws, size_t ws_size,
                              hipStream_t stream) {
    fp x      = (fp)d_in[0];
    fp rbf    = (fp)d_in[1];
    const int* ei = (const int*)d_in[2];
    fp ntm_w  = (fp)d_in[3];
    fp ntm_b  = (fp)d_in[4];
    fp rtm_w  = (fp)d_in[5];
    fp rtm_b  = (fp)d_in[6];
    fp norm_g = (fp)d_in[7];
    fp norm_b = (fp)d_in[8];
    fp l1_w   = (fp)d_in[9];
    fp l1_b   = (fp)d_in[10];
    fp ln_g   = (fp)d_in[11];
    fp ln_b   = (fp)d_in[12];
    fp l2_w   = (fp)d_in[13];
    fp l2_b   = (fp)d_in[14];
    fp mtn_w  = (fp)d_in[15];

    const int N = in_sizes[0] / HD;            // 50000
    const int E = in_sizes[2] / 2;             // 800000

    // workspace layout (16B-aligned chunks)
    char* wp = (char*)d_ws;
    float*    agg    = (float*)wp;              wp += (size_t)N * FD * 4;
    ushort_t* xfb    = (ushort_t*)wp;           wp += (size_t)N * FD * 2;
    ushort_t* W1p    = (ushort_t*)wp;           wp += (size_t)FD * K1DIM * 2;
    ushort_t* W2p    = (ushort_t*)wp;           wp += (size_t)FD * FD * 2;
    float*    bias1p = (float*)wp;              wp += FD * 4;
    ushort_t* W0p    = (ushort_t*)wp;           wp += (size_t)FD * HD * 2;
    ushort_t* Wm     = (ushort_t*)wp;           wp += (size_t)HD * FD * 2;

    hipMemsetAsync((void*)agg, 0, (size_t)N * FD * sizeof(float), stream);

    prep_weights<<<FD, 128, 0, stream>>>(l1_w, l1_b, rtm_w, rtm_b, l2_w,
                                         ntm_w, mtn_w, W1p, W2p, bias1p, W0p, Wm);

    const int ntilesN = (N + EB - 1) / EB;     // 782
    node_xform_mfma<<<ntilesN, 256, 0, stream>>>(x, W0p, ntm_b, norm_g, norm_b,
                                                 xfb, N, ntilesN);

    const int ntilesE = (E + EB - 1) / EB;     // 12500
    const int nblk = ntilesE < 500 ? ntilesE : 500;
    edge_mlp_mfma<<<nblk, 256, 0, stream>>>(rbf, ei, E, ntilesE, W1p, W2p, bias1p,
                                            ln_g, ln_b, l2_b, xfb, agg);

    node_out_mfma<<<ntilesN, 256, 0, stream>>>(agg, Wm, (float*)d_out, N, ntilesN);
}